// Round 1
// baseline (943.301 us; speedup 1.0000x reference)
//
#include <hip/hip_runtime.h>
#include <stdint.h>

#define NN 100000
#define EE 1600000
#define DD 64
#define NB 391   // ceil(NN/256)

// ---------------- CSR build ----------------

__global__ void count_kernel(const int* __restrict__ dst, int* __restrict__ cnt) {
    int e = blockIdx.x * blockDim.x + threadIdx.x;
    if (e < EE) atomicAdd(&cnt[dst[e]], 1);
}

__global__ void scan1(const int* __restrict__ cnt, int* __restrict__ partial) {
    __shared__ int s[256];
    int i = blockIdx.x * 256 + threadIdx.x;
    int v = (i < NN) ? cnt[i] : 0;
    s[threadIdx.x] = v;
    __syncthreads();
    for (int off = 128; off > 0; off >>= 1) {
        if (threadIdx.x < off) s[threadIdx.x] += s[threadIdx.x + off];
        __syncthreads();
    }
    if (threadIdx.x == 0) partial[blockIdx.x] = s[0];
}

__global__ void scan2(int* __restrict__ partial) {
    // exclusive scan of NB block sums, single block of 512 threads
    __shared__ int s[512];
    int t = threadIdx.x;
    int v = (t < NB) ? partial[t] : 0;
    s[t] = v;
    __syncthreads();
    for (int off = 1; off < 512; off <<= 1) {
        int add = (t >= off) ? s[t - off] : 0;
        __syncthreads();
        s[t] += add;
        __syncthreads();
    }
    if (t < NB) partial[t] = s[t] - v;  // exclusive
}

__global__ void scan3(const int* __restrict__ cnt, const int* __restrict__ partial,
                      int* __restrict__ offsets, int* __restrict__ cursor) {
    __shared__ int s[256];
    int t = threadIdx.x;
    int i = blockIdx.x * 256 + t;
    int v = (i < NN) ? cnt[i] : 0;
    s[t] = v;
    __syncthreads();
    for (int off = 1; off < 256; off <<= 1) {
        int add = (t >= off) ? s[t - off] : 0;
        __syncthreads();
        s[t] += add;
        __syncthreads();
    }
    int excl = s[t] - v + partial[blockIdx.x];
    if (i < NN) {
        offsets[i] = excl;
        cursor[i]  = excl;
        if (i == NN - 1) offsets[NN] = excl + v;
    }
}

__global__ void scatter_kernel(const int* __restrict__ src, const int* __restrict__ dst,
                               int* __restrict__ cursor, int* __restrict__ csr) {
    int e = blockIdx.x * blockDim.x + threadIdx.x;
    if (e < EE) {
        int d = dst[e];
        int pos = atomicAdd(&cursor[d], 1);
        csr[pos] = src[e];
    }
}

// ---------------- fused 3-way GEMM: Y[i][0:64]=h@Wl+bl, [64:128]=h@Wr+br, [128:192]=h@Ws+bs ----------------

__global__ __launch_bounds__(256) void gemm_fused(
    const float* __restrict__ hin,
    const float* __restrict__ Wl, const float* __restrict__ Wr, const float* __restrict__ Ws,
    const float* __restrict__ bl, const float* __restrict__ br, const float* __restrict__ bs,
    float* __restrict__ Y) {
    __shared__ float Wlds[64][192];
    __shared__ float bias[192];
    __shared__ float ht[32][64];
    int t = threadIdx.x;
    for (int idx = t; idx < 64 * 64; idx += 256) {
        int k = idx >> 6, c = idx & 63;
        Wlds[k][c]        = Wl[idx];
        Wlds[k][64 + c]   = Wr[idx];
        Wlds[k][128 + c]  = Ws[idx];
    }
    if (t < 64) { bias[t] = bl[t]; bias[64 + t] = br[t]; bias[128 + t] = bs[t]; }
    int row0 = blockIdx.x * 32;
    for (int idx = t; idx < 32 * 64; idx += 256) {
        ht[idx >> 6][idx & 63] = hin[(size_t)(row0 + (idx >> 6)) * 64 + (idx & 63)];
    }
    __syncthreads();

    int c  = t & 63;
    int rg = t >> 6;  // 0..3
    float acc0[8], acc1[8], acc2[8];
#pragma unroll
    for (int r = 0; r < 8; r++) { acc0[r] = 0.f; acc1[r] = 0.f; acc2[r] = 0.f; }
#pragma unroll 4
    for (int k = 0; k < 64; k++) {
        float w0 = Wlds[k][c], w1 = Wlds[k][64 + c], w2 = Wlds[k][128 + c];
#pragma unroll
        for (int rr = 0; rr < 8; rr++) {
            float hv = ht[rg + rr * 4][k];
            acc0[rr] += hv * w0;
            acc1[rr] += hv * w1;
            acc2[rr] += hv * w2;
        }
    }
    float b0 = bias[c], b1 = bias[64 + c], b2 = bias[128 + c];
#pragma unroll
    for (int rr = 0; rr < 8; rr++) {
        size_t row = row0 + rg + rr * 4;
        Y[row * 192 + c]        = acc0[rr] + b0;
        Y[row * 192 + 64 + c]   = acc1[rr] + b1;
        Y[row * 192 + 128 + c]  = acc2[rr] + b2;
    }
}

// ---------------- per-node attention aggregation (one wave per dst node) ----------------

__global__ __launch_bounds__(256) void node_kernel(
    const float* __restrict__ Y, const int* __restrict__ offsets,
    const int* __restrict__ csr, const float* __restrict__ att,
    const float* __restrict__ bg, float* __restrict__ hout, int do_relu) {
    int lane = threadIdx.x & 63;
    int wid  = threadIdx.x >> 6;
    int i = blockIdx.x * 4 + wid;
    if (i >= NN) return;
    float xr   = Y[(size_t)i * 192 + 64 + lane];
    float attk = att[lane];
    float agg = 0.f, denom = 0.f;
    int beg = offsets[i], end = offsets[i + 1];
    for (int j = beg; j < end; j++) {
        int s = csr[j];
        float xls = Y[(size_t)s * 192 + lane];
        float v = xls + xr;
        v = (v > 0.f) ? v : 0.2f * v;
        float tsum = v * attk;
#pragma unroll
        for (int m = 1; m < 64; m <<= 1) tsum += __shfl_xor(tsum, m, 64);
        float a = __expf(tsum);   // softmax max-shift skipped: invariant, |e| small
        agg   += a * xls;
        denom += a;
    }
    float inv = (denom > 0.f) ? (1.0f / denom) : 0.f;
    float res = agg * inv + bg[lane] + Y[(size_t)i * 192 + 128 + lane];
    if (do_relu) res = (res > 0.f) ? res : 0.f;
    hout[(size_t)i * 64 + lane] = res;
}

// ---------------- final projection out = h @ Wout + bout ----------------

__global__ __launch_bounds__(256) void out_kernel(
    const float* __restrict__ h, const float* __restrict__ Wout,
    const float* __restrict__ bout, float* __restrict__ out) {
    int lane = threadIdx.x & 63;
    int wid  = threadIdx.x >> 6;
    int i = blockIdx.x * 4 + wid;
    if (i >= NN) return;
    float p  = h[(size_t)i * 64 + lane];
    float a0 = p * Wout[lane * 2 + 0];
    float a1 = p * Wout[lane * 2 + 1];
#pragma unroll
    for (int m = 1; m < 64; m <<= 1) {
        a0 += __shfl_xor(a0, m, 64);
        a1 += __shfl_xor(a1, m, 64);
    }
    if (lane == 0) {
        out[(size_t)i * 2 + 0] = a0 + bout[0];
        out[(size_t)i * 2 + 1] = a1 + bout[1];
    }
}

// ---------------- launch ----------------

extern "C" void kernel_launch(void* const* d_in, const int* in_sizes, int n_in,
                              void* d_out, int out_size, void* d_ws, size_t ws_size,
                              hipStream_t stream) {
    const float* x    = (const float*)d_in[0];
    const int*   ei   = (const int*)d_in[1];   // [2][E]: row0=src, row1=dst
    const float* Wl   = (const float*)d_in[2];
    const float* bl   = (const float*)d_in[3];
    const float* Wr   = (const float*)d_in[4];
    const float* br   = (const float*)d_in[5];
    const float* att  = (const float*)d_in[6];
    const float* bg   = (const float*)d_in[7];
    const float* Ws   = (const float*)d_in[8];
    const float* bs   = (const float*)d_in[9];
    const float* Wout = (const float*)d_in[10];
    const float* bout = (const float*)d_in[11];
    float* out = (float*)d_out;

    size_t off = 0;
    char* base = (char*)d_ws;
    auto alloc = [&](size_t bytes) -> void* {
        void* p = base + off;
        off += (bytes + 255) & ~(size_t)255;
        return p;
    };
    float* Y      = (float*)alloc((size_t)NN * 192 * 4);
    float* h      = (float*)alloc((size_t)NN * 64 * 4);
    int*   cnt    = (int*)alloc((size_t)NN * 4);
    int*   offs   = (int*)alloc((size_t)(NN + 1) * 4);
    int*   cursor = (int*)alloc((size_t)NN * 4);
    int*   csr    = (int*)alloc((size_t)EE * 4);
    int*   part   = (int*)alloc(512 * 4);

    const int* src = ei;
    const int* dst = ei + EE;

    hipMemsetAsync(cnt, 0, (size_t)NN * 4, stream);
    count_kernel<<<(EE + 255) / 256, 256, 0, stream>>>(dst, cnt);
    scan1<<<NB, 256, 0, stream>>>(cnt, part);
    scan2<<<1, 512, 0, stream>>>(part);
    scan3<<<NB, 256, 0, stream>>>(cnt, part, offs, cursor);
    scatter_kernel<<<(EE + 255) / 256, 256, 0, stream>>>(src, dst, cursor, csr);

    const float* hin = x;
    for (int L = 0; L < 3; L++) {
        gemm_fused<<<NN / 32, 256, 0, stream>>>(
            hin, Wl + L * 4096, Wr + L * 4096, Ws + L * 4096,
            bl + L * 64, br + L * 64, bs + L * 64, Y);
        node_kernel<<<NN / 4, 256, 0, stream>>>(
            Y, offs, csr, att + L * 64, bg + L * 64, h, (L < 2) ? 1 : 0);
        hin = h;
    }
    out_kernel<<<NN / 4, 256, 0, stream>>>(h, Wout, bout, out);
}

// Round 2
// 654.184 us; speedup vs baseline: 1.4420x; 1.4420x over previous
//
#include <hip/hip_runtime.h>
#include <stdint.h>

#define NN 100000
#define EE 1600000
#define DD 64
#define NB 391   // ceil(NN/256)

// ---------------- CSR build ----------------

__global__ void count_kernel(const int* __restrict__ dst, int* __restrict__ cnt) {
    int e = blockIdx.x * blockDim.x + threadIdx.x;
    if (e < EE) atomicAdd(&cnt[dst[e]], 1);
}

__global__ void scan1(const int* __restrict__ cnt, int* __restrict__ partial) {
    __shared__ int s[256];
    int i = blockIdx.x * 256 + threadIdx.x;
    int v = (i < NN) ? cnt[i] : 0;
    s[threadIdx.x] = v;
    __syncthreads();
    for (int off = 128; off > 0; off >>= 1) {
        if (threadIdx.x < off) s[threadIdx.x] += s[threadIdx.x + off];
        __syncthreads();
    }
    if (threadIdx.x == 0) partial[blockIdx.x] = s[0];
}

__global__ void scan2(int* __restrict__ partial) {
    __shared__ int s[512];
    int t = threadIdx.x;
    int v = (t < NB) ? partial[t] : 0;
    s[t] = v;
    __syncthreads();
    for (int off = 1; off < 512; off <<= 1) {
        int add = (t >= off) ? s[t - off] : 0;
        __syncthreads();
        s[t] += add;
        __syncthreads();
    }
    if (t < NB) partial[t] = s[t] - v;  // exclusive
}

__global__ void scan3(const int* __restrict__ cnt, const int* __restrict__ partial,
                      int* __restrict__ offsets, int* __restrict__ cursor) {
    __shared__ int s[256];
    int t = threadIdx.x;
    int i = blockIdx.x * 256 + t;
    int v = (i < NN) ? cnt[i] : 0;
    s[t] = v;
    __syncthreads();
    for (int off = 1; off < 256; off <<= 1) {
        int add = (t >= off) ? s[t - off] : 0;
        __syncthreads();
        s[t] += add;
        __syncthreads();
    }
    int excl = s[t] - v + partial[blockIdx.x];
    if (i < NN) {
        offsets[i] = excl;
        cursor[i]  = excl;
        if (i == NN - 1) offsets[NN] = excl + v;
    }
}

__global__ void scatter_kernel(const int* __restrict__ src, const int* __restrict__ dst,
                               int* __restrict__ cursor, int* __restrict__ csr) {
    int e = blockIdx.x * blockDim.x + threadIdx.x;
    if (e < EE) {
        int d = dst[e];
        int pos = atomicAdd(&cursor[d], 1);
        csr[pos] = src[e];
    }
}

// ---------------- fused 3-way GEMM: Y[i][0:64]=h@Wl+bl, [64:128]=h@Wr+br, [128:192]=h@Ws+bs ----------------

__global__ __launch_bounds__(256) void gemm_fused(
    const float* __restrict__ hin,
    const float* __restrict__ Wl, const float* __restrict__ Wr, const float* __restrict__ Ws,
    const float* __restrict__ bl, const float* __restrict__ br, const float* __restrict__ bs,
    float* __restrict__ Y) {
    __shared__ float Wlds[64][192];
    __shared__ float bias[192];
    __shared__ float ht[32][64];
    int t = threadIdx.x;
    for (int idx = t; idx < 64 * 64; idx += 256) {
        int k = idx >> 6, c = idx & 63;
        Wlds[k][c]        = Wl[idx];
        Wlds[k][64 + c]   = Wr[idx];
        Wlds[k][128 + c]  = Ws[idx];
    }
    if (t < 64) { bias[t] = bl[t]; bias[64 + t] = br[t]; bias[128 + t] = bs[t]; }
    int row0 = blockIdx.x * 32;
    for (int idx = t; idx < 32 * 64; idx += 256) {
        ht[idx >> 6][idx & 63] = hin[(size_t)(row0 + (idx >> 6)) * 64 + (idx & 63)];
    }
    __syncthreads();

    int c  = t & 63;
    int rg = t >> 6;  // 0..3 -> rows rg*8 .. rg*8+7 (thread-consecutive for float4 h reads)
    float acc0[8], acc1[8], acc2[8];
#pragma unroll
    for (int r = 0; r < 8; r++) { acc0[r] = 0.f; acc1[r] = 0.f; acc2[r] = 0.f; }
#pragma unroll 2
    for (int k0 = 0; k0 < 64; k0 += 4) {
        float w0[4], w1[4], w2[4];
#pragma unroll
        for (int kk = 0; kk < 4; kk++) {
            w0[kk] = Wlds[k0 + kk][c];
            w1[kk] = Wlds[k0 + kk][64 + c];
            w2[kk] = Wlds[k0 + kk][128 + c];
        }
#pragma unroll
        for (int rr = 0; rr < 8; rr++) {
            float4 hv = *(const float4*)&ht[rg * 8 + rr][k0];  // broadcast b128
            acc0[rr] += hv.x * w0[0] + hv.y * w0[1] + hv.z * w0[2] + hv.w * w0[3];
            acc1[rr] += hv.x * w1[0] + hv.y * w1[1] + hv.z * w1[2] + hv.w * w1[3];
            acc2[rr] += hv.x * w2[0] + hv.y * w2[1] + hv.z * w2[2] + hv.w * w2[3];
        }
    }
    float b0 = bias[c], b1 = bias[64 + c], b2 = bias[128 + c];
#pragma unroll
    for (int rr = 0; rr < 8; rr++) {
        size_t row = row0 + rg * 8 + rr;
        Y[row * 192 + c]        = acc0[rr] + b0;
        Y[row * 192 + 64 + c]   = acc1[rr] + b1;
        Y[row * 192 + 128 + c]  = acc2[rr] + b2;
    }
}

// ---------------- per-node attention aggregation (one wave per dst node) ----------------

// Full-wave sum-reduce, all lanes get the total.
// xor1,xor2 via DPP quad_perm; xor4,xor8 via row_half_mirror/row_mirror (valid because
// quads are uniform after xor1+xor2, so mirror == xor); xor16 via ds_swizzle; xor32 via shfl.
__device__ __forceinline__ float wave_sum64(float t) {
    t += __int_as_float(__builtin_amdgcn_update_dpp(0, __float_as_int(t), 0xB1, 0xF, 0xF, true));   // xor1
    t += __int_as_float(__builtin_amdgcn_update_dpp(0, __float_as_int(t), 0x4E, 0xF, 0xF, true));   // xor2
    t += __int_as_float(__builtin_amdgcn_update_dpp(0, __float_as_int(t), 0x141, 0xF, 0xF, true));  // row_half_mirror ~ xor4
    t += __int_as_float(__builtin_amdgcn_update_dpp(0, __float_as_int(t), 0x140, 0xF, 0xF, true));  // row_mirror ~ xor8
    t += __int_as_float(__builtin_amdgcn_ds_swizzle(__float_as_int(t), 0x401F));                    // xor16
    t += __shfl_xor(t, 32, 64);                                                                     // xor32
    return t;
}

__device__ __forceinline__ float lrelu(float v) {
    return (v > 0.f) ? v : 0.2f * v;
}

__global__ __launch_bounds__(256) void node_kernel(
    const float* __restrict__ Y, const int* __restrict__ offsets,
    const int* __restrict__ csr, const float* __restrict__ att,
    const float* __restrict__ bg, float* __restrict__ hout, int do_relu) {
    int lane = threadIdx.x & 63;
    int wid  = threadIdx.x >> 6;
    int i = blockIdx.x * 4 + wid;
    if (i >= NN) return;
    float xr   = Y[(size_t)i * 192 + 64 + lane];
    float attk = att[lane];
    float agg = 0.f, denom = 0.f;
    int beg = offsets[i], end = offsets[i + 1];
    int j = beg;
    // 4-wide unroll: 4 independent gather+reduce chains in flight
    for (; j + 4 <= end; j += 4) {
        int s0 = csr[j], s1 = csr[j + 1], s2 = csr[j + 2], s3 = csr[j + 3];
        float x0 = Y[(size_t)s0 * 192 + lane];
        float x1 = Y[(size_t)s1 * 192 + lane];
        float x2 = Y[(size_t)s2 * 192 + lane];
        float x3 = Y[(size_t)s3 * 192 + lane];
        float t0 = lrelu(x0 + xr) * attk;
        float t1 = lrelu(x1 + xr) * attk;
        float t2 = lrelu(x2 + xr) * attk;
        float t3 = lrelu(x3 + xr) * attk;
        t0 = wave_sum64(t0);
        t1 = wave_sum64(t1);
        t2 = wave_sum64(t2);
        t3 = wave_sum64(t3);
        float a0 = __expf(t0), a1 = __expf(t1), a2 = __expf(t2), a3 = __expf(t3);
        agg += a0 * x0 + a1 * x1 + a2 * x2 + a3 * x3;
        denom += (a0 + a1) + (a2 + a3);
    }
    for (; j < end; j++) {
        int s = csr[j];
        float xls = Y[(size_t)s * 192 + lane];
        float tsum = wave_sum64(lrelu(xls + xr) * attk);
        float a = __expf(tsum);
        agg   += a * xls;
        denom += a;
    }
    float inv = (denom > 0.f) ? (1.0f / denom) : 0.f;
    float res = agg * inv + bg[lane] + Y[(size_t)i * 192 + 128 + lane];
    if (do_relu) res = (res > 0.f) ? res : 0.f;
    hout[(size_t)i * 64 + lane] = res;
}

// ---------------- final projection out = h @ Wout + bout ----------------

__global__ __launch_bounds__(256) void out_kernel(
    const float* __restrict__ h, const float* __restrict__ Wout,
    const float* __restrict__ bout, float* __restrict__ out) {
    int lane = threadIdx.x & 63;
    int wid  = threadIdx.x >> 6;
    int i = blockIdx.x * 4 + wid;
    if (i >= NN) return;
    float p  = h[(size_t)i * 64 + lane];
    float a0 = p * Wout[lane * 2 + 0];
    float a1 = p * Wout[lane * 2 + 1];
#pragma unroll
    for (int m = 1; m < 64; m <<= 1) {
        a0 += __shfl_xor(a0, m, 64);
        a1 += __shfl_xor(a1, m, 64);
    }
    if (lane == 0) {
        out[(size_t)i * 2 + 0] = a0 + bout[0];
        out[(size_t)i * 2 + 1] = a1 + bout[1];
    }
}

// ---------------- launch ----------------

extern "C" void kernel_launch(void* const* d_in, const int* in_sizes, int n_in,
                              void* d_out, int out_size, void* d_ws, size_t ws_size,
                              hipStream_t stream) {
    const float* x    = (const float*)d_in[0];
    const int*   ei   = (const int*)d_in[1];   // [2][E]: row0=src, row1=dst
    const float* Wl   = (const float*)d_in[2];
    const float* bl   = (const float*)d_in[3];
    const float* Wr   = (const float*)d_in[4];
    const float* br   = (const float*)d_in[5];
    const float* att  = (const float*)d_in[6];
    const float* bg   = (const float*)d_in[7];
    const float* Ws   = (const float*)d_in[8];
    const float* bs   = (const float*)d_in[9];
    const float* Wout = (const float*)d_in[10];
    const float* bout = (const float*)d_in[11];
    float* out = (float*)d_out;

    size_t off = 0;
    char* base = (char*)d_ws;
    auto alloc = [&](size_t bytes) -> void* {
        void* p = base + off;
        off += (bytes + 255) & ~(size_t)255;
        return p;
    };
    float* Y      = (float*)alloc((size_t)NN * 192 * 4);
    float* h      = (float*)alloc((size_t)NN * 64 * 4);
    int*   cnt    = (int*)alloc((size_t)NN * 4);
    int*   offs   = (int*)alloc((size_t)(NN + 1) * 4);
    int*   cursor = (int*)alloc((size_t)NN * 4);
    int*   csr    = (int*)alloc((size_t)EE * 4);
    int*   part   = (int*)alloc(512 * 4);

    const int* src = ei;
    const int* dst = ei + EE;

    hipMemsetAsync(cnt, 0, (size_t)NN * 4, stream);
    count_kernel<<<(EE + 255) / 256, 256, 0, stream>>>(dst, cnt);
    scan1<<<NB, 256, 0, stream>>>(cnt, part);
    scan2<<<1, 512, 0, stream>>>(part);
    scan3<<<NB, 256, 0, stream>>>(cnt, part, offs, cursor);
    scatter_kernel<<<(EE + 255) / 256, 256, 0, stream>>>(src, dst, cursor, csr);

    const float* hin = x;
    for (int L = 0; L < 3; L++) {
        gemm_fused<<<NN / 32, 256, 0, stream>>>(
            hin, Wl + L * 4096, Wr + L * 4096, Ws + L * 4096,
            bl + L * 64, br + L * 64, bs + L * 64, Y);
        node_kernel<<<NN / 4, 256, 0, stream>>>(
            Y, offs, csr, att + L * 64, bg + L * 64, h, (L < 2) ? 1 : 0);
        hin = h;
    }
    out_kernel<<<NN / 4, 256, 0, stream>>>(h, Wout, bout, out);
}